// Round 4
// baseline (208.600 us; speedup 1.0000x reference)
//
#include <hip/hip_runtime.h>
#include <math.h>

// Side-window filter, 3 iterations fused, FP32 throughout, emulating the
// reference's arithmetic: each directional conv = sequential fp32 FMA chain
// over taps in row-major (ky,kx) order with acc starting at 0 (GEMM/im2col
// semantics), weights = fp32-rounded 1/15, 1/9, (1/9)/9. Zero-padded taps are
// exact no-ops in the chain. Intermediates stay fp32; out-of-image
// intermediate pixels are zeroed (next iteration zero-pads at image boundary).
//
// Direction supports (with the reference's normalization bug):
//   d0 L  = rows[-2..2] x cols[-2..0] * (1/15)
//   d1 R  = rows[-2..2] x cols[0..2]  * (1/15)
//   d2 U  = rows[-2..0] x cols[-2..2] * (1/15)
//   d3 D  = rows[0..2]  x cols[-2..2] * (1/15)
//   d4 NW = rows[-2..0] x cols[-2..0] * (1/9)
//   d5 NE = NW support * (1/81)   (bug: NE = new NW / 9)
//   d6 SW = rows[0..2]  x cols[-2..0] * (1/9)
//   d7 SE = SW support * (1/81)   (bug: SE = new SW / 9)

typedef float f4 __attribute__((ext_vector_type(4)));

#define TW 64
#define TH 24

// One SWF iteration. X: (H2+4) x (W2+4) fp32 tile (pitch W2+4), zero-padded.
// Y: H2 x W2 output (pitch W2), zeroed outside the 768x768 image
// (gy0,gx0 = global coords of Y[0][0]); if LAST, write fp32 to outp (pitch 768).
template<int H2, int W2, bool LAST>
__device__ __forceinline__ void step(const float* __restrict__ X,
                                     float* __restrict__ Y,
                                     float* __restrict__ outp,
                                     int gy0, int gx0, int tid) {
    constexpr int PW = W2 + 4;
    const float w15 = 1.0f / 15.0f;          // fp32(1/15)
    const float w9  = 1.0f / 9.0f;           // fp32(1/9)
    const float w81 = (1.0f / 9.0f) / 9.0f;  // fp32(fp32(1/9)/9)

    constexpr int SC = W2 / 4;
    constexpr int NSEG = H2 * SC;
    for (int s = tid; s < NSEG; s += 256) {
        const int y  = s / SC;
        const int xs = (s - y * SC) * 4;
        // register window: rows y..y+4, tile cols xs..xs+7
        float Wv[5][8];
        #pragma unroll
        for (int r = 0; r < 5; r++) {
            const float* p = X + (y + r) * PW + xs;
            *(f4*)&Wv[r][0] = *(const f4*)p;
            *(f4*)&Wv[r][4] = *(const f4*)(p + 4);
        }
        #pragma unroll
        for (int j = 0; j < 4; j++) {
            const float c = Wv[2][j + 2];
            // sequential row-major FMA chains, one per direction
            float aL = 0.0f, aR = 0.0f, aU = 0.0f, aD = 0.0f;
            float aNW = 0.0f, aNE = 0.0f, aSW = 0.0f, aSE = 0.0f;
            #pragma unroll
            for (int r = 0; r < 5; r++)
                #pragma unroll
                for (int cc = 0; cc < 3; cc++)
                    aL = fmaf(w15, Wv[r][j + cc], aL);
            #pragma unroll
            for (int r = 0; r < 5; r++)
                #pragma unroll
                for (int cc = 2; cc < 5; cc++)
                    aR = fmaf(w15, Wv[r][j + cc], aR);
            #pragma unroll
            for (int r = 0; r < 3; r++)
                #pragma unroll
                for (int cc = 0; cc < 5; cc++)
                    aU = fmaf(w15, Wv[r][j + cc], aU);
            #pragma unroll
            for (int r = 2; r < 5; r++)
                #pragma unroll
                for (int cc = 0; cc < 5; cc++)
                    aD = fmaf(w15, Wv[r][j + cc], aD);
            #pragma unroll
            for (int r = 0; r < 3; r++)
                #pragma unroll
                for (int cc = 0; cc < 3; cc++) {
                    aNW = fmaf(w9,  Wv[r][j + cc], aNW);
                    aNE = fmaf(w81, Wv[r][j + cc], aNE);
                }
            #pragma unroll
            for (int r = 2; r < 5; r++)
                #pragma unroll
                for (int cc = 0; cc < 3; cc++) {
                    aSW = fmaf(w9,  Wv[r][j + cc], aSW);
                    aSE = fmaf(w81, Wv[r][j + cc], aSE);
                }

            const float d0 = aL - c, d1 = aR - c, d2 = aU - c, d3 = aD - c;
            const float d4 = aNW - c, d5 = aNE - c, d6 = aSW - c, d7 = aSE - c;

            // first-index-wins argmin over |d| (matches jnp.argmin)
            float best = fabsf(d0), bd = d0, a;
            a = fabsf(d1); if (a < best) { best = a; bd = d1; }
            a = fabsf(d2); if (a < best) { best = a; bd = d2; }
            a = fabsf(d3); if (a < best) { best = a; bd = d3; }
            a = fabsf(d4); if (a < best) { best = a; bd = d4; }
            a = fabsf(d5); if (a < best) { best = a; bd = d5; }
            a = fabsf(d6); if (a < best) { best = a; bd = d6; }
            a = fabsf(d7); if (a < best) { best = a; bd = d7; }

            const float res = c + bd;
            if (LAST) {
                outp[y * 768 + xs + j] = res;
            } else {
                const bool inside = ((unsigned)(gy0 + y) < 768u) &&
                                    ((unsigned)(gx0 + xs + j) < 768u);
                Y[y * W2 + xs + j] = inside ? res : 0.0f;
            }
        }
    }
    __syncthreads();
}

// LDS: A = 36x76 fp32 (iter1 input; reused as iter2 output 28x68),
//      B = 32x72 fp32 (iter1 output = iter2 input). 20160 B total.
__global__ __launch_bounds__(256) void swf_fused(const float* __restrict__ in,
                                                 float* __restrict__ out) {
    __shared__ __align__(16) float A[36 * 76];
    __shared__ __align__(16) float B[32 * 72];

    const int tid = threadIdx.x;
    const int tx0 = blockIdx.x * TW;
    const int ty0 = blockIdx.y * TH;
    const long long base = (long long)blockIdx.z * (768 * 768);
    const float* inp = in + base;

    // load tile rows ty0-6..ty0+29, cols tx0-6..tx0+69, zero-padded
    for (int i = tid; i < 36 * 76; i += 256) {
        int ly = i / 76, lx = i - ly * 76;
        int gy = ty0 + ly - 6, gx = tx0 + lx - 6;
        float v = 0.0f;
        if ((unsigned)gy < 768u && (unsigned)gx < 768u)
            v = inp[gy * 768 + gx];
        A[i] = v;
    }
    __syncthreads();

    step<32, 72, false>(A, B, nullptr, ty0 - 4, tx0 - 4, tid);  // iter1: A->B
    step<28, 68, false>(B, A, nullptr, ty0 - 2, tx0 - 2, tid);  // iter2: B->A
    step<24, 64, true >(A, nullptr,                              // iter3: A->out
                        out + base + (long long)ty0 * 768 + tx0, ty0, tx0, tid);
}

extern "C" void kernel_launch(void* const* d_in, const int* in_sizes, int n_in,
                              void* d_out, int out_size, void* d_ws, size_t ws_size,
                              hipStream_t stream) {
    const float* x = (const float*)d_in[0];
    float* out = (float*)d_out;

    dim3 grid(768 / TW, 768 / TH, 24);   // 12 x 32 x 24 blocks
    dim3 block(256);
    swf_fused<<<grid, block, 0, stream>>>(x, out);
}